// Round 1
// baseline (626.757 us; speedup 1.0000x reference)
//
#include <hip/hip_runtime.h>

#define T_STEPS 256
#define BATCH   128
#define FEAT    1536            // DH * L = 512 * 3
#define NPAIRS  (T_STEPS * BATCH)

__device__ __forceinline__ float sigm(float x) {
    x = fminf(fmaxf(x, -30.f), 30.f);
    return 1.f / (1.f + __expf(-x));
}

__device__ __forceinline__ float tanh_fast(float x) {
    x = fminf(fmaxf(x, -15.f), 15.f);
    float e = __expf(2.f * x);
    return (e - 1.f) / (e + 1.f);
}

// ---------------------------------------------------------------------------
// Kernel 1: X[t,b,o] = dot(inputs[t,b,:,:], Wi[o]) + bi[o]
// One wave per (t,b) pair (grid-stride). float4 coalesced loads, Wi fragments
// preloaded into registers once per wave.
// ---------------------------------------------------------------------------
__global__ __launch_bounds__(256) void xdot_kernel(
    const float* __restrict__ x,    // (T*B, 1536)
    const float* __restrict__ Wi,   // (2, 1536)
    const float* __restrict__ bi,   // (2,)
    float* __restrict__ X)          // (T*B, 2)
{
    const int lane   = threadIdx.x & 63;
    const int wave   = (blockIdx.x * blockDim.x + threadIdx.x) >> 6;
    const int nwaves = (gridDim.x * blockDim.x) >> 6;

    const float4* Wi0 = (const float4*)(Wi);
    const float4* Wi1 = (const float4*)(Wi + FEAT);
    float4 w0[6], w1[6];
#pragma unroll
    for (int k = 0; k < 6; ++k) {
        w0[k] = Wi0[lane + 64 * k];
        w1[k] = Wi1[lane + 64 * k];
    }
    const float b0 = bi[0], b1 = bi[1];

    for (int p = wave; p < NPAIRS; p += nwaves) {
        const float4* xp = (const float4*)(x + (size_t)p * FEAT);
        float a0 = 0.f, a1 = 0.f;
#pragma unroll
        for (int k = 0; k < 6; ++k) {
            float4 v = xp[lane + 64 * k];
            a0 += v.x * w0[k].x + v.y * w0[k].y + v.z * w0[k].z + v.w * w0[k].w;
            a1 += v.x * w1[k].x + v.y * w1[k].y + v.z * w1[k].z + v.w * w1[k].w;
        }
#pragma unroll
        for (int s = 32; s > 0; s >>= 1) {
            a0 += __shfl_xor(a0, s, 64);
            a1 += __shfl_xor(a1, s, 64);
        }
        if (lane == 0) {
            X[2 * p]     = a0 + b0;
            X[2 * p + 1] = a1 + b1;
        }
    }
}

// ---------------------------------------------------------------------------
// Kernel 2: the sequential scan. One block of 256 threads per batch element.
// State h,c lives in registers: thread owns float4 [4*tid .. 4*tid+3] and
// float2 [1024 + 2*tid .. +1]  (all coalesced for loads/stores).
// Per step: 4 block reductions (wave shuffle + LDS cross-wave, double-buffered
// -> ONE __syncthreads per step), scalar gates, tanh, store ht.
// ---------------------------------------------------------------------------
__global__ __launch_bounds__(256) void scan_kernel(
    const float* __restrict__ h0,
    const float* __restrict__ c0,
    const float* __restrict__ Wr, const float* __restrict__ br,
    const float* __restrict__ Wc, const float* __restrict__ bc,
    const float* __restrict__ X,    // (T*B, 2)
    float* __restrict__ outs,       // (T*B, 1536)
    float* __restrict__ hT,         // (B, 1536)
    float* __restrict__ cT)         // (B, 1536)
{
    const int b    = blockIdx.x;
    const int tid  = threadIdx.x;
    const int wid  = tid >> 6;
    const int lane = tid & 63;

    __shared__ float red[2][16];    // double-buffered: 4 waves x 4 values

    // weight fragments (leading 1024 floats as float4, tail 512 as float2)
    const float4 wr0_4 = ((const float4*)Wr)[tid];
    const float4 wr1_4 = ((const float4*)(Wr + FEAT))[tid];
    const float2 wr0_2 = ((const float2*)(Wr + 1024))[tid];
    const float2 wr1_2 = ((const float2*)(Wr + FEAT + 1024))[tid];
    const float4 wc0_4 = ((const float4*)Wc)[tid];
    const float4 wc1_4 = ((const float4*)(Wc + FEAT))[tid];
    const float2 wc0_2 = ((const float2*)(Wc + 1024))[tid];
    const float2 wc1_2 = ((const float2*)(Wc + FEAT + 1024))[tid];
    const float br0 = br[0], br1 = br[1];
    const float bc0 = bc[0], bc1 = bc[1];

    const float* h0b = h0 + (size_t)b * FEAT;
    const float* c0b = c0 + (size_t)b * FEAT;
    float4 h4 = ((const float4*)h0b)[tid];
    float2 h2 = ((const float2*)(h0b + 1024))[tid];
    float4 c4 = ((const float4*)c0b)[tid];
    float2 c2 = ((const float2*)(c0b + 1024))[tid];

    for (int t = 0; t < T_STEPS; ++t) {
        // per-batch scalars from the pre-pass (block-uniform -> scalar load)
        const float Xc = X[(t * BATCH + b) * 2 + 0];
        const float Xh = X[(t * BATCH + b) * 2 + 1];

        // partial dots over this thread's 6 elements
        float pHc = h4.x * wr0_4.x + h4.y * wr0_4.y + h4.z * wr0_4.z + h4.w * wr0_4.w
                  + h2.x * wr0_2.x + h2.y * wr0_2.y;
        float pHh = h4.x * wr1_4.x + h4.y * wr1_4.y + h4.z * wr1_4.z + h4.w * wr1_4.w
                  + h2.x * wr1_2.x + h2.y * wr1_2.y;
        float pCc = c4.x * wc0_4.x + c4.y * wc0_4.y + c4.z * wc0_4.z + c4.w * wc0_4.w
                  + c2.x * wc0_2.x + c2.y * wc0_2.y;
        float pCh = c4.x * wc1_4.x + c4.y * wc1_4.y + c4.z * wc1_4.z + c4.w * wc1_4.w
                  + c2.x * wc1_2.x + c2.y * wc1_2.y;

#pragma unroll
        for (int s = 32; s > 0; s >>= 1) {
            pHc += __shfl_xor(pHc, s, 64);
            pHh += __shfl_xor(pHh, s, 64);
            pCc += __shfl_xor(pCc, s, 64);
            pCh += __shfl_xor(pCh, s, 64);
        }
        float* buf = red[t & 1];
        if (lane == 0) {
            buf[wid * 4 + 0] = pHc;
            buf[wid * 4 + 1] = pHh;
            buf[wid * 4 + 2] = pCc;
            buf[wid * 4 + 3] = pCh;
        }
        __syncthreads();
        const float Hc = buf[0] + buf[4] + buf[8]  + buf[12] + br0;
        const float Hh = buf[1] + buf[5] + buf[9]  + buf[13] + br1;
        const float Cc = buf[2] + buf[6] + buf[10] + buf[14] + bc0;
        const float Ch = buf[3] + buf[7] + buf[11] + buf[15] + bc1;

        // gates:
        //   gh = (1 - sig(Ch)) * Xh + (1 - sig(Hh)) * h
        //   gc = (1 - sig(Hc)) * Xc + (1 - sig(Cc)) * c
        const float Ah = (1.f - sigm(Ch)) * Xh;
        const float Sh = (1.f - sigm(Hh));
        const float Ac = (1.f - sigm(Hc)) * Xc;
        const float Sc = (1.f - sigm(Cc));

        h4.x = tanh_fast(Ah + Sh * h4.x);
        h4.y = tanh_fast(Ah + Sh * h4.y);
        h4.z = tanh_fast(Ah + Sh * h4.z);
        h4.w = tanh_fast(Ah + Sh * h4.w);
        h2.x = tanh_fast(Ah + Sh * h2.x);
        h2.y = tanh_fast(Ah + Sh * h2.y);

        c4.x = tanh_fast(Ac + Sc * c4.x);
        c4.y = tanh_fast(Ac + Sc * c4.y);
        c4.z = tanh_fast(Ac + Sc * c4.z);
        c4.w = tanh_fast(Ac + Sc * c4.w);
        c2.x = tanh_fast(Ac + Sc * c2.x);
        c2.y = tanh_fast(Ac + Sc * c2.y);

        // outs[t, b, :] = ht   (coalesced dwordx4 + dwordx2 stores)
        float* op = outs + (size_t)(t * BATCH + b) * FEAT;
        ((float4*)op)[tid]          = h4;
        ((float2*)(op + 1024))[tid] = h2;
        // NOTE: no second barrier needed — red[] is double-buffered and the
        // single barrier per step separates write/read of each buffer.
    }

    float* hp = hT + (size_t)b * FEAT;
    ((float4*)hp)[tid]          = h4;
    ((float2*)(hp + 1024))[tid] = h2;
    float* cp = cT + (size_t)b * FEAT;
    ((float4*)cp)[tid]          = c4;
    ((float2*)(cp + 1024))[tid] = c2;
}

extern "C" void kernel_launch(void* const* d_in, const int* in_sizes, int n_in,
                              void* d_out, int out_size, void* d_ws, size_t ws_size,
                              hipStream_t stream) {
    const float* inputs = (const float*)d_in[0];
    const float* h0     = (const float*)d_in[1];
    const float* c0     = (const float*)d_in[2];
    const float* Wr     = (const float*)d_in[3];
    const float* br     = (const float*)d_in[4];
    const float* Wc     = (const float*)d_in[5];
    const float* bc     = (const float*)d_in[6];
    const float* Wi     = (const float*)d_in[7];
    const float* bi     = (const float*)d_in[8];

    float* out = (float*)d_out;
    float* X   = (float*)d_ws;               // needs 256 KiB: (T*B, 2) floats

    float* outs = out;                                        // (T,B,1536)
    float* hT   = out + (size_t)NPAIRS * FEAT;                // (B,1536)
    float* cT   = hT + (size_t)BATCH * FEAT;                  // (B,1536)

    xdot_kernel<<<1024, 256, 0, stream>>>(inputs, Wi, bi, X);
    scan_kernel<<<BATCH, 256, 0, stream>>>(h0, c0, Wr, br, Wc, bc, X,
                                           outs, hT, cT);
}

// Round 2
// 512.974 us; speedup vs baseline: 1.2218x; 1.2218x over previous
//
#include <hip/hip_runtime.h>

#define T_STEPS 256
#define BATCH   128
#define FEAT    1536            // DH * L = 512 * 3
#define NPAIRS  (T_STEPS * BATCH)

// ---------------------------------------------------------------------------
// DPP full-wave (64-lane) sum. Result valid in lane 63.
// row_shr:1/2/4/8 builds per-16-row sums (lanes 15/31/47/63),
// row_bcast:15 (rows 1,3) then row_bcast:31 (rows 2,3) combine rows.
// All VALU-pipe: ~8 cyc per level vs ~120 for ds_swizzle-based __shfl.
// ---------------------------------------------------------------------------
template <int CTRL, int RMASK>
__device__ __forceinline__ float dpp_add_step(float v) {
    int m = __builtin_amdgcn_update_dpp(0, __float_as_int(v), CTRL, RMASK, 0xF, true);
    return v + __int_as_float(m);
}

__device__ __forceinline__ float wave_reduce63(float v) {
    v = dpp_add_step<0x111, 0xF>(v);   // row_shr:1
    v = dpp_add_step<0x112, 0xF>(v);   // row_shr:2
    v = dpp_add_step<0x114, 0xF>(v);   // row_shr:4
    v = dpp_add_step<0x118, 0xF>(v);   // row_shr:8  -> lanes 15/31/47/63 = row sums
    v = dpp_add_step<0x142, 0xA>(v);   // row_bcast:15 into rows 1,3
    v = dpp_add_step<0x143, 0xC>(v);   // row_bcast:31 into rows 2,3 -> lane63 = total
    return v;
}

// 1 - sigmoid(x) = 1/(1 + e^x); inf-safe without clamps (rcp(inf)=0).
__device__ __forceinline__ float one_minus_sig(float x) {
    float e = exp2f(x * 1.4426950408889634f);
    return __builtin_amdgcn_rcpf(1.0f + e);
}

// tanh(x) = (e^{2x}-1)/(e^{2x}+1); only upper clamp needed (exp2f(-big)=0).
__device__ __forceinline__ float tanh_fast(float x) {
    float t = fminf(x, 10.0f);
    float e = exp2f(t * 2.8853900817779268f);
    return (e - 1.0f) * __builtin_amdgcn_rcpf(e + 1.0f);
}

// ---------------------------------------------------------------------------
// Kernel 1: X[b,t,o] = dot(inputs[t,b,:,:], Wi[o]) + bi[o]
// One block (256 threads) per (t,b) pair: 6 floats/thread, DPP reduce,
// tiny LDS cross-wave combine. 32768 blocks -> pure HBM-bound streaming.
// Output stored TRANSPOSED as (b, t) float2 so scan's LDS staging load
// is coalesced.
// ---------------------------------------------------------------------------
__global__ __launch_bounds__(256) void xdot_kernel(
    const float* __restrict__ x,    // (T*B, 1536)
    const float* __restrict__ Wi,   // (2, 1536)
    const float* __restrict__ bi,   // (2,)
    float* __restrict__ X)          // (B, T) float2
{
    const int p    = blockIdx.x;           // t*BATCH + b
    const int tid  = threadIdx.x;
    const int wid  = tid >> 6;
    const int lane = tid & 63;

    __shared__ float red[8];               // 4 waves x 2 partials

    const float* xp = x + (size_t)p * FEAT;
    const float4 v4 = ((const float4*)xp)[tid];
    const float2 v2 = ((const float2*)(xp + 1024))[tid];

    const float4 w04 = ((const float4*)Wi)[tid];
    const float2 w02 = ((const float2*)(Wi + 1024))[tid];
    const float4 w14 = ((const float4*)(Wi + FEAT))[tid];
    const float2 w12 = ((const float2*)(Wi + FEAT + 1024))[tid];

    float a0 = v4.x * w04.x + v4.y * w04.y + v4.z * w04.z + v4.w * w04.w
             + v2.x * w02.x + v2.y * w02.y;
    float a1 = v4.x * w14.x + v4.y * w14.y + v4.z * w14.z + v4.w * w14.w
             + v2.x * w12.x + v2.y * w12.y;

    a0 = wave_reduce63(a0);
    a1 = wave_reduce63(a1);
    if (lane == 63) {
        red[wid * 2]     = a0;
        red[wid * 2 + 1] = a1;
    }
    __syncthreads();
    if (tid == 0) {
        const float s0 = red[0] + red[2] + red[4] + red[6] + bi[0];
        const float s1 = red[1] + red[3] + red[5] + red[7] + bi[1];
        const int b = p & (BATCH - 1);
        const int t = p >> 7;                    // p / BATCH
        ((float2*)X)[b * T_STEPS + t] = make_float2(s0, s1);
    }
}

// ---------------------------------------------------------------------------
// Kernel 2: sequential scan, one 256-thread block per batch element.
// h,c in registers (6 floats/thread). Per step: 24 FMAs, 4 DPP wave
// reductions, one ds_write_b128/wave + ONE barrier (double-buffered red[]),
// 4 broadcast ds_read_b128, 4 rcp/exp2 gates, 12 tanh, coalesced stores.
// X pre-staged in LDS (one coalesced load at kernel start).
// ---------------------------------------------------------------------------
__global__ __launch_bounds__(256) void scan_kernel(
    const float* __restrict__ h0,
    const float* __restrict__ c0,
    const float* __restrict__ Wr, const float* __restrict__ br,
    const float* __restrict__ Wc, const float* __restrict__ bc,
    const float* __restrict__ X,    // (B, T) float2
    float* __restrict__ outs,       // (T*B, 1536)
    float* __restrict__ hT,         // (B, 1536)
    float* __restrict__ cT)         // (B, 1536)
{
    const int b    = blockIdx.x;
    const int tid  = threadIdx.x;
    const int wid  = tid >> 6;
    const int lane = tid & 63;

    __shared__ float  red[2][16];   // double-buffered: 4 waves x 4 values
    __shared__ float2 Xsh[T_STEPS];

    // stage this batch's X into LDS (coalesced: X is (b,t) float2)
    Xsh[tid] = ((const float2*)X)[b * T_STEPS + tid];

    const float4 wr0_4 = ((const float4*)Wr)[tid];
    const float4 wr1_4 = ((const float4*)(Wr + FEAT))[tid];
    const float2 wr0_2 = ((const float2*)(Wr + 1024))[tid];
    const float2 wr1_2 = ((const float2*)(Wr + FEAT + 1024))[tid];
    const float4 wc0_4 = ((const float4*)Wc)[tid];
    const float4 wc1_4 = ((const float4*)(Wc + FEAT))[tid];
    const float2 wc0_2 = ((const float2*)(Wc + 1024))[tid];
    const float2 wc1_2 = ((const float2*)(Wc + FEAT + 1024))[tid];
    const float br0 = br[0], br1 = br[1];
    const float bc0 = bc[0], bc1 = bc[1];

    const float* h0b = h0 + (size_t)b * FEAT;
    const float* c0b = c0 + (size_t)b * FEAT;
    float4 h4 = ((const float4*)h0b)[tid];
    float2 h2 = ((const float2*)(h0b + 1024))[tid];
    float4 c4 = ((const float4*)c0b)[tid];
    float2 c2 = ((const float2*)(c0b + 1024))[tid];

    __syncthreads();   // Xsh visible

    for (int t = 0; t < T_STEPS; ++t) {
        const float2 Xv = Xsh[t];   // LDS broadcast; hoisted early by scheduler

        float pHc = h4.x * wr0_4.x + h4.y * wr0_4.y + h4.z * wr0_4.z + h4.w * wr0_4.w
                  + h2.x * wr0_2.x + h2.y * wr0_2.y;
        float pHh = h4.x * wr1_4.x + h4.y * wr1_4.y + h4.z * wr1_4.z + h4.w * wr1_4.w
                  + h2.x * wr1_2.x + h2.y * wr1_2.y;
        float pCc = c4.x * wc0_4.x + c4.y * wc0_4.y + c4.z * wc0_4.z + c4.w * wc0_4.w
                  + c2.x * wc0_2.x + c2.y * wc0_2.y;
        float pCh = c4.x * wc1_4.x + c4.y * wc1_4.y + c4.z * wc1_4.z + c4.w * wc1_4.w
                  + c2.x * wc1_2.x + c2.y * wc1_2.y;

        pHc = wave_reduce63(pHc);
        pHh = wave_reduce63(pHh);
        pCc = wave_reduce63(pCc);
        pCh = wave_reduce63(pCh);

        float* buf = red[t & 1];
        if (lane == 63) {
            *(float4*)&buf[wid * 4] = make_float4(pHc, pHh, pCc, pCh);
        }
        __syncthreads();
        const float4 r0 = *(const float4*)&buf[0];
        const float4 r1 = *(const float4*)&buf[4];
        const float4 r2 = *(const float4*)&buf[8];
        const float4 r3 = *(const float4*)&buf[12];
        const float Hc = r0.x + r1.x + r2.x + r3.x + br0;
        const float Hh = r0.y + r1.y + r2.y + r3.y + br1;
        const float Cc = r0.z + r1.z + r2.z + r3.z + bc0;
        const float Ch = r0.w + r1.w + r2.w + r3.w + bc1;

        // gh = (1-sig(Ch))*Xh + (1-sig(Hh))*h ; gc = (1-sig(Hc))*Xc + (1-sig(Cc))*c
        const float Ah = one_minus_sig(Ch) * Xv.y;
        const float Sh = one_minus_sig(Hh);
        const float Ac = one_minus_sig(Hc) * Xv.x;
        const float Sc = one_minus_sig(Cc);

        h4.x = tanh_fast(Ah + Sh * h4.x);
        h4.y = tanh_fast(Ah + Sh * h4.y);
        h4.z = tanh_fast(Ah + Sh * h4.z);
        h4.w = tanh_fast(Ah + Sh * h4.w);
        h2.x = tanh_fast(Ah + Sh * h2.x);
        h2.y = tanh_fast(Ah + Sh * h2.y);

        c4.x = tanh_fast(Ac + Sc * c4.x);
        c4.y = tanh_fast(Ac + Sc * c4.y);
        c4.z = tanh_fast(Ac + Sc * c4.z);
        c4.w = tanh_fast(Ac + Sc * c4.w);
        c2.x = tanh_fast(Ac + Sc * c2.x);
        c2.y = tanh_fast(Ac + Sc * c2.y);

        float* op = outs + (size_t)(t * BATCH + b) * FEAT;
        ((float4*)op)[tid]          = h4;
        ((float2*)(op + 1024))[tid] = h2;
        // One barrier/step is safe: red[] is double-buffered, and a wave can
        // only reach the write of red[t&1] (at step t+2) after barrier t+1,
        // by which point every wave has completed its step-t read.
    }

    float* hp = hT + (size_t)b * FEAT;
    ((float4*)hp)[tid]          = h4;
    ((float2*)(hp + 1024))[tid] = h2;
    float* cp = cT + (size_t)b * FEAT;
    ((float4*)cp)[tid]          = c4;
    ((float2*)(cp + 1024))[tid] = c2;
}

extern "C" void kernel_launch(void* const* d_in, const int* in_sizes, int n_in,
                              void* d_out, int out_size, void* d_ws, size_t ws_size,
                              hipStream_t stream) {
    const float* inputs = (const float*)d_in[0];
    const float* h0     = (const float*)d_in[1];
    const float* c0     = (const float*)d_in[2];
    const float* Wr     = (const float*)d_in[3];
    const float* br     = (const float*)d_in[4];
    const float* Wc     = (const float*)d_in[5];
    const float* bc     = (const float*)d_in[6];
    const float* Wi     = (const float*)d_in[7];
    const float* bi     = (const float*)d_in[8];

    float* out = (float*)d_out;
    float* X   = (float*)d_ws;               // 256 KiB: (B, T) float2

    float* outs = out;                                        // (T,B,1536)
    float* hT   = out + (size_t)NPAIRS * FEAT;                // (B,1536)
    float* cT   = hT + (size_t)BATCH * FEAT;                  // (B,1536)

    xdot_kernel<<<NPAIRS, 256, 0, stream>>>(inputs, Wi, bi, X);
    scan_kernel<<<BATCH, 256, 0, stream>>>(h0, c0, Wr, br, Wc, bc, X,
                                           outs, hT, cT);
}

// Round 3
// 449.101 us; speedup vs baseline: 1.3956x; 1.1422x over previous
//
#include <hip/hip_runtime.h>

#define T_STEPS 256
#define BATCH   128
#define FEAT    1536            // DH * L = 512 * 3
#define NPAIRS  (T_STEPS * BATCH)

// ---------------------------------------------------------------------------
// DPP full-wave (64-lane) sum. Result valid in lane 63. All VALU-pipe.
// ---------------------------------------------------------------------------
template <int CTRL, int RMASK>
__device__ __forceinline__ float dpp_add_step(float v) {
    int m = __builtin_amdgcn_update_dpp(0, __float_as_int(v), CTRL, RMASK, 0xF, true);
    return v + __int_as_float(m);
}

__device__ __forceinline__ float wave_reduce63(float v) {
    v = dpp_add_step<0x111, 0xF>(v);   // row_shr:1
    v = dpp_add_step<0x112, 0xF>(v);   // row_shr:2
    v = dpp_add_step<0x114, 0xF>(v);   // row_shr:4
    v = dpp_add_step<0x118, 0xF>(v);   // row_shr:8  -> lanes 15/31/47/63
    v = dpp_add_step<0x142, 0xA>(v);   // row_bcast:15 into rows 1,3
    v = dpp_add_step<0x143, 0xC>(v);   // row_bcast:31 into rows 2,3
    return v;
}

// 1 - sigmoid(x) = 1/(1 + e^x); inf-safe without clamps (rcp(inf)=0).
__device__ __forceinline__ float one_minus_sig(float x) {
    float e = __builtin_amdgcn_exp2f(x * 1.4426950408889634f);
    return __builtin_amdgcn_rcpf(1.0f + e);
}

// tanh(x) = 1 - 2/(1 + e^{2x}); saturates correctly at +/-inf, no clamps.
__device__ __forceinline__ float tanh_fast(float x) {
    float e = __builtin_amdgcn_exp2f(x * 2.8853900817779268f);
    return fmaf(-2.0f, __builtin_amdgcn_rcpf(1.0f + e), 1.0f);
}

// LDS-only barrier: orders ds_write/ds_read across waves WITHOUT draining
// the outstanding global stores (__syncthreads would emit s_waitcnt vmcnt(0)
// before s_barrier, putting HBM store latency on the serial scan path).
__device__ __forceinline__ void barrier_lds_only() {
    asm volatile("s_waitcnt lgkmcnt(0)\n\ts_barrier" ::: "memory");
}

// ---------------------------------------------------------------------------
// Kernel 1: X[b,t,o] = dot(inputs[t,b,:,:], Wi[o]) + bi[o]
// One block (256 threads) per (t,b) pair. Output transposed (b,t) so scan's
// LDS staging load is coalesced.
// ---------------------------------------------------------------------------
__global__ __launch_bounds__(256) void xdot_kernel(
    const float* __restrict__ x,    // (T*B, 1536)
    const float* __restrict__ Wi,   // (2, 1536)
    const float* __restrict__ bi,   // (2,)
    float* __restrict__ X)          // (B, T) float2
{
    const int p    = blockIdx.x;           // t*BATCH + b
    const int tid  = threadIdx.x;
    const int wid  = tid >> 6;
    const int lane = tid & 63;

    __shared__ float red[8];               // 4 waves x 2 partials

    const float* xp = x + (size_t)p * FEAT;
    const float4 v4 = ((const float4*)xp)[tid];
    const float2 v2 = ((const float2*)(xp + 1024))[tid];

    const float4 w04 = ((const float4*)Wi)[tid];
    const float2 w02 = ((const float2*)(Wi + 1024))[tid];
    const float4 w14 = ((const float4*)(Wi + FEAT))[tid];
    const float2 w12 = ((const float2*)(Wi + FEAT + 1024))[tid];

    float a0 = v4.x * w04.x + v4.y * w04.y + v4.z * w04.z + v4.w * w04.w
             + v2.x * w02.x + v2.y * w02.y;
    float a1 = v4.x * w14.x + v4.y * w14.y + v4.z * w14.z + v4.w * w14.w
             + v2.x * w12.x + v2.y * w12.y;

    a0 = wave_reduce63(a0);
    a1 = wave_reduce63(a1);
    if (lane == 63) {
        red[wid * 2]     = a0;
        red[wid * 2 + 1] = a1;
    }
    __syncthreads();
    if (tid == 0) {
        const float s0 = red[0] + red[2] + red[4] + red[6] + bi[0];
        const float s1 = red[1] + red[3] + red[5] + red[7] + bi[1];
        const int b = p & (BATCH - 1);
        const int t = p >> 7;                    // p / BATCH
        ((float2*)X)[b * T_STEPS + t] = make_float2(s0, s1);
    }
}

// ---------------------------------------------------------------------------
// Kernel 2: sequential scan, one 256-thread block per batch element.
// h,c in registers (6 floats/thread). Per step: 24 FMAs, 4 DPP wave
// reductions, one ds_write/wave + ONE lgkm-only barrier (double-buffered
// red[]), 4 gate evals, 12 tanh, coalesced global stores that are never
// drained inside the loop. Manually unrolled x2 (static buffer index).
// ---------------------------------------------------------------------------
__global__ __launch_bounds__(256) void scan_kernel(
    const float* __restrict__ h0,
    const float* __restrict__ c0,
    const float* __restrict__ Wr, const float* __restrict__ br,
    const float* __restrict__ Wc, const float* __restrict__ bc,
    const float* __restrict__ X,    // (B, T) float2
    float* __restrict__ outs,       // (T*B, 1536)
    float* __restrict__ hT,         // (B, 1536)
    float* __restrict__ cT)         // (B, 1536)
{
    const int b    = blockIdx.x;
    const int tid  = threadIdx.x;
    const int wid  = tid >> 6;
    const int lane = tid & 63;

    __shared__ float4 red[2][4];    // double-buffered: 4 waves x (Hc,Hh,Cc,Ch)
    __shared__ float2 Xsh[T_STEPS];

    // stage this batch's X into LDS (coalesced: X is (b,t) float2)
    Xsh[tid] = ((const float2*)X)[b * T_STEPS + tid];

    const float4 wr0_4 = ((const float4*)Wr)[tid];
    const float4 wr1_4 = ((const float4*)(Wr + FEAT))[tid];
    const float2 wr0_2 = ((const float2*)(Wr + 1024))[tid];
    const float2 wr1_2 = ((const float2*)(Wr + FEAT + 1024))[tid];
    const float4 wc0_4 = ((const float4*)Wc)[tid];
    const float4 wc1_4 = ((const float4*)(Wc + FEAT))[tid];
    const float2 wc0_2 = ((const float2*)(Wc + 1024))[tid];
    const float2 wc1_2 = ((const float2*)(Wc + FEAT + 1024))[tid];
    const float br0 = br[0], br1 = br[1];
    const float bc0 = bc[0], bc1 = bc[1];

    const float* h0b = h0 + (size_t)b * FEAT;
    const float* c0b = c0 + (size_t)b * FEAT;
    float4 h4 = ((const float4*)h0b)[tid];
    float2 h2 = ((const float2*)(h0b + 1024))[tid];
    float4 c4 = ((const float4*)c0b)[tid];
    float2 c2 = ((const float2*)(c0b + 1024))[tid];

    float* op = outs + (size_t)b * FEAT;
    const size_t OSTRIDE = (size_t)BATCH * FEAT;

    __syncthreads();   // Xsh visible (one-time; vmcnt drain harmless here)

    auto step = [&](float4* buf, int t) {
        const float2 Xv = Xsh[t];   // LDS broadcast, hoistable (t-only dep)

        float pHc = h4.x * wr0_4.x + h4.y * wr0_4.y + h4.z * wr0_4.z + h4.w * wr0_4.w
                  + h2.x * wr0_2.x + h2.y * wr0_2.y;
        float pHh = h4.x * wr1_4.x + h4.y * wr1_4.y + h4.z * wr1_4.z + h4.w * wr1_4.w
                  + h2.x * wr1_2.x + h2.y * wr1_2.y;
        float pCc = c4.x * wc0_4.x + c4.y * wc0_4.y + c4.z * wc0_4.z + c4.w * wc0_4.w
                  + c2.x * wc0_2.x + c2.y * wc0_2.y;
        float pCh = c4.x * wc1_4.x + c4.y * wc1_4.y + c4.z * wc1_4.z + c4.w * wc1_4.w
                  + c2.x * wc1_2.x + c2.y * wc1_2.y;

        pHc = wave_reduce63(pHc);
        pHh = wave_reduce63(pHh);
        pCc = wave_reduce63(pCc);
        pCh = wave_reduce63(pCh);

        if (lane == 63) {
            buf[wid] = make_float4(pHc, pHh, pCc, pCh);
        }
        barrier_lds_only();
        const float4 r0 = buf[0];
        const float4 r1 = buf[1];
        const float4 r2 = buf[2];
        const float4 r3 = buf[3];
        const float Hc = r0.x + r1.x + r2.x + r3.x + br0;
        const float Hh = r0.y + r1.y + r2.y + r3.y + br1;
        const float Cc = r0.z + r1.z + r2.z + r3.z + bc0;
        const float Ch = r0.w + r1.w + r2.w + r3.w + bc1;

        // gh = (1-sig(Ch))*Xh + (1-sig(Hh))*h ; gc = (1-sig(Hc))*Xc + (1-sig(Cc))*c
        const float Ah = one_minus_sig(Ch) * Xv.y;
        const float Sh = one_minus_sig(Hh);
        const float Ac = one_minus_sig(Hc) * Xv.x;
        const float Sc = one_minus_sig(Cc);

        h4.x = tanh_fast(fmaf(Sh, h4.x, Ah));
        h4.y = tanh_fast(fmaf(Sh, h4.y, Ah));
        h4.z = tanh_fast(fmaf(Sh, h4.z, Ah));
        h4.w = tanh_fast(fmaf(Sh, h4.w, Ah));
        h2.x = tanh_fast(fmaf(Sh, h2.x, Ah));
        h2.y = tanh_fast(fmaf(Sh, h2.y, Ah));

        c4.x = tanh_fast(fmaf(Sc, c4.x, Ac));
        c4.y = tanh_fast(fmaf(Sc, c4.y, Ac));
        c4.z = tanh_fast(fmaf(Sc, c4.z, Ac));
        c4.w = tanh_fast(fmaf(Sc, c4.w, Ac));
        c2.x = tanh_fast(fmaf(Sc, c2.x, Ac));
        c2.y = tanh_fast(fmaf(Sc, c2.y, Ac));

        // outs[t, b, :] = ht (fire-and-forget; never drained inside the loop)
        ((float4*)op)[tid]          = h4;
        ((float2*)(op + 1024))[tid] = h2;
        op += OSTRIDE;
        // Double-buffer safety with ONE barrier/step: a wave's re-write of
        // buf (step t+2) happens after barrier t+1, which every wave reaches
        // only after its step-t read of this buffer.
    };

#pragma unroll 1
    for (int t = 0; t < T_STEPS; t += 2) {
        step(red[0], t);
        step(red[1], t + 1);
    }

    float* hp = hT + (size_t)b * FEAT;
    ((float4*)hp)[tid]          = h4;
    ((float2*)(hp + 1024))[tid] = h2;
    float* cp = cT + (size_t)b * FEAT;
    ((float4*)cp)[tid]          = c4;
    ((float2*)(cp + 1024))[tid] = c2;
}

extern "C" void kernel_launch(void* const* d_in, const int* in_sizes, int n_in,
                              void* d_out, int out_size, void* d_ws, size_t ws_size,
                              hipStream_t stream) {
    const float* inputs = (const float*)d_in[0];
    const float* h0     = (const float*)d_in[1];
    const float* c0     = (const float*)d_in[2];
    const float* Wr     = (const float*)d_in[3];
    const float* br     = (const float*)d_in[4];
    const float* Wc     = (const float*)d_in[5];
    const float* bc     = (const float*)d_in[6];
    const float* Wi     = (const float*)d_in[7];
    const float* bi     = (const float*)d_in[8];

    float* out = (float*)d_out;
    float* X   = (float*)d_ws;               // 256 KiB: (B, T) float2

    float* outs = out;                                        // (T,B,1536)
    float* hT   = out + (size_t)NPAIRS * FEAT;                // (B,1536)
    float* cT   = hT + (size_t)BATCH * FEAT;                  // (B,1536)

    xdot_kernel<<<NPAIRS, 256, 0, stream>>>(inputs, Wi, bi, X);
    scan_kernel<<<BATCH, 256, 0, stream>>>(h0, c0, Wr, br, Wc, bc, X,
                                           outs, hT, cT);
}